// Round 1
// baseline (383.055 us; speedup 1.0000x reference)
//
#include <hip/hip_runtime.h>

// Problem constants (from reference)
constexpr int Bn = 512;
constexpr int Nn = 1024;
constexpr int Kn = 8;
constexpr int Pn = 2016;
constexpr int H1 = 128;
constexpr int H2 = 64;
constexpr int NC = 40;

constexpr int TP  = 132;   // padded LDS stride for T rows: (k*132+h)%32 = (4k+h)%32 -> distinct bank quads per k
constexpr int RPB = 512;   // rows per block
constexpr int BPB = 4;     // blocks per batch (4*512 >= 2016)

__global__ __launch_bounds__(256, 2)
void fused_mlp_kernel(const float* __restrict__ x,
                      const int*   __restrict__ idx,
                      const int*   __restrict__ perms,
                      const float* __restrict__ W1, const float* __restrict__ b1,
                      const float* __restrict__ W2, const float* __restrict__ b2,
                      const float* __restrict__ W3, const float* __restrict__ b3,
                      float* __restrict__ out)
{
    __shared__ float T[8][8][TP];      // T[s][k][h] = sum_c pts[k][c]*W1[3s+c][h] (+b1 at s==0)
    __shared__ float ptsl[Kn * 3];
    __shared__ float wred[4][H2];

    const int t   = threadIdx.x;
    const int b   = blockIdx.x / BPB;
    const int pib = blockIdx.x % BPB;
    const int p0  = pib * RPB;

    // ---- load the 8 sampled points (24 floats) ----
    if (t < Kn * 3) {
        const int k = t / 3, c = t % 3;
        ptsl[t] = x[b * (Nn * 3) + idx[k] * 3 + c];
    }
    __syncthreads();

    // ---- build T in LDS: 8192 elems, 32 per thread ----
    #pragma unroll 1
    for (int i = 0; i < 32; ++i) {
        const int e = t + (i << 8);
        const int s = e >> 10;
        const int k = (e >> 7) & 7;
        const int h = e & 127;
        float v = ptsl[k * 3 + 0] * W1[(3 * s + 0) * H1 + h]
                + ptsl[k * 3 + 1] * W1[(3 * s + 1) * H1 + h]
                + ptsl[k * 3 + 2] * W1[(3 * s + 2) * H1 + h];
        if (s == 0) v += b1[h];     // fold b1: every row uses exactly one T[0][k]
        T[s][k][h] = v;
    }
    __syncthreads();

    const int wave = t >> 6;
    const int lane = t & 63;

    // running sum over rows of relu(h2) -- layer 3 is linear, commutes with mean
    float hsum[H2];
    #pragma unroll
    for (int j = 0; j < H2; ++j) hsum[j] = 0.f;

    #pragma unroll 1
    for (int grp = wave; grp < RPB / 64; grp += 4) {
        const int p = p0 + grp * 64 + lane;
        if (p < Pn) {
            const int* pp = perms + (b * Pn + p) * Kn;
            int pr[8];
            #pragma unroll
            for (int s = 0; s < 8; ++s) pr[s] = pp[s];

            float acc[H2];
            #pragma unroll
            for (int j = 0; j < H2; ++j) acc[j] = b2[j];   // uniform loads

            #pragma unroll 1
            for (int kc = 0; kc < H1; kc += 16) {
                // ---- layer 1 chunk: h1[kc..kc+16) = sum_s T[s][pr[s]][kc..] ----
                float4 a[4];
                {
                    const float4* t0 = (const float4*)(&T[0][pr[0]][kc]);
                    #pragma unroll
                    for (int q = 0; q < 4; ++q) a[q] = t0[q];
                }
                #pragma unroll
                for (int s = 1; s < 8; ++s) {
                    const float4* ts = (const float4*)(&T[s][pr[s]][kc]);
                    #pragma unroll
                    for (int q = 0; q < 4; ++q) {
                        const float4 v = ts[q];
                        a[q].x += v.x; a[q].y += v.y; a[q].z += v.z; a[q].w += v.w;
                    }
                }
                // ---- layer 2 partial: acc[j] += relu(h1[k]) * W2[k][j] ----
                #pragma unroll
                for (int q = 0; q < 4; ++q) {
                    const float e0 = fmaxf(a[q].x, 0.f);
                    const float e1 = fmaxf(a[q].y, 0.f);
                    const float e2 = fmaxf(a[q].z, 0.f);
                    const float e3 = fmaxf(a[q].w, 0.f);
                    const float* w0 = W2 + (kc + q * 4 + 0) * H2;
                    const float* w1 = W2 + (kc + q * 4 + 1) * H2;
                    const float* w2 = W2 + (kc + q * 4 + 2) * H2;
                    const float* w3 = W2 + (kc + q * 4 + 3) * H2;
                    #pragma unroll
                    for (int j = 0; j < H2; ++j) {
                        float v = acc[j];
                        v = fmaf(e0, w0[j], v);   // w*[j] is wave-uniform -> s_load + v_fmac v,s,v
                        v = fmaf(e1, w1[j], v);
                        v = fmaf(e2, w2[j], v);
                        v = fmaf(e3, w3[j], v);
                        acc[j] = v;
                    }
                }
            }
            #pragma unroll
            for (int j = 0; j < H2; ++j) hsum[j] += fmaxf(acc[j], 0.f);
        }
    }

    // ---- reduce hsum across lanes (shuffle), then waves (LDS) ----
    #pragma unroll
    for (int j = 0; j < H2; ++j) {
        float v = hsum[j];
        v += __shfl_down(v, 32);
        v += __shfl_down(v, 16);
        v += __shfl_down(v, 8);
        v += __shfl_down(v, 4);
        v += __shfl_down(v, 2);
        v += __shfl_down(v, 1);
        if (lane == 0) wred[wave][j] = v;
    }
    __syncthreads();

    if (t < H2) {
        wred[0][t] = wred[0][t] + wred[1][t] + wred[2][t] + wred[3][t];
    }
    __syncthreads();

    // ---- layer 3 once per block: y[c] = b3[c] + (1/P) * sum_j W3[j][c]*Hsum[j] ----
    if (t < NC) {
        constexpr float invP = 1.f / (float)Pn;
        float s = 0.f;
        #pragma unroll
        for (int j = 0; j < H2; ++j) s = fmaf(W3[j * NC + t], wred[0][j], s);
        const float base = (pib == 0) ? b3[t] : 0.f;
        atomicAdd(&out[b * NC + t], base + s * invP);
    }
}

extern "C" void kernel_launch(void* const* d_in, const int* in_sizes, int n_in,
                              void* d_out, int out_size, void* d_ws, size_t ws_size,
                              hipStream_t stream) {
    const float* x     = (const float*)d_in[0];
    const int*   idx   = (const int*)  d_in[1];
    const int*   perms = (const int*)  d_in[2];
    const float* W1    = (const float*)d_in[3];
    const float* b1    = (const float*)d_in[4];
    const float* W2    = (const float*)d_in[5];
    const float* b2    = (const float*)d_in[6];
    const float* W3    = (const float*)d_in[7];
    const float* b3    = (const float*)d_in[8];
    float* out = (float*)d_out;

    hipMemsetAsync(out, 0, (size_t)out_size * sizeof(float), stream);

    dim3 grid(Bn * BPB);
    dim3 block(256);
    hipLaunchKernelGGL(fused_mlp_kernel, grid, block, 0, stream,
                       x, idx, perms, W1, b1, W2, b2, W3, b3, out);
}

// Round 3
// 307.927 us; speedup vs baseline: 1.2440x; 1.2440x over previous
//
#include <hip/hip_runtime.h>

typedef __bf16 bf16x8 __attribute__((ext_vector_type(8)));
typedef short  s16x8  __attribute__((ext_vector_type(8)));
typedef float  f32x16 __attribute__((ext_vector_type(16)));

constexpr int Bn = 512;
constexpr int Nn = 1024;
constexpr int Pn = 2016;
constexpr int H1c = 128;
constexpr int H2c = 64;
constexpr int NCc = 40;

// split fp32 v into bf16 hi + bf16 lo (v ~= hi + lo), round-to-nearest-even
__device__ __forceinline__ void split2(float v, unsigned short& hi, unsigned short& lo) {
    unsigned u  = __float_as_uint(v);
    unsigned r  = u + 0x7fffu + ((u >> 16) & 1u);
    hi = (unsigned short)(r >> 16);
    float hf = __uint_as_float(r & 0xffff0000u);
    unsigned u2 = __float_as_uint(v - hf);
    unsigned r2 = u2 + 0x7fffu + ((u2 >> 16) & 1u);
    lo = (unsigned short)(r2 >> 16);
}

// Pre-split W2 (128x64 f32) into MFMA-A-fragment-ready bf16 hi/lo arrays in ws.
// Layout: idx = (((c*2+nt)*2 + half)*32 + col)*8 + jj
//   value = split(W2[k][j]), k = c*16 + half*8 + jj, j = nt*32 + col
// so lane (half,col) of a wave reads its 8 bf16 (16B) contiguously per (c,nt).
__global__ void prep_w2(const float* __restrict__ W2,
                        unsigned short* __restrict__ hi,
                        unsigned short* __restrict__ lo) {
    int i = blockIdx.x * 256 + threadIdx.x;
    if (i >= 8192) return;
    int jj = i & 7, colm = (i >> 3) & 31, kh = (i >> 8) & 1, nt = (i >> 9) & 1, c = i >> 10;
    int k = c * 16 + kh * 8 + jj;
    int j = nt * 32 + colm;
    unsigned short h, l;
    split2(W2[k * H2c + j], h, l);
    hi[i] = h;
    lo[i] = l;
}

__global__ __launch_bounds__(512, 2)
void mlp_mfma(const float* __restrict__ x, const int* __restrict__ idx,
              const int* __restrict__ perms,
              const float* __restrict__ W1, const float* __restrict__ b1,
              const float* __restrict__ b2,
              const float* __restrict__ W3, const float* __restrict__ b3,
              const unsigned short* __restrict__ w2hi,
              const unsigned short* __restrict__ w2lo,
              float* __restrict__ out)
{
    // T2[g][p][h] (g<4, p=k1*8+k2<64, h<128) stored swizzled at float4 granularity:
    // float index = ((g*64+p)*32 + ((h>>2) ^ (p&7)))*4 + (h&3)
    __shared__ float T2f[4 * 64 * 128];      // 128 KiB
    __shared__ float ptsl[24];
    __shared__ float wred[8][64];
    __shared__ float Hs[64];

    const int t   = threadIdx.x;
    const int b   = blockIdx.x >> 2;
    const int pib = blockIdx.x & 3;

    if (t < 24) {
        int k = t / 3, c = t % 3;
        ptsl[t] = x[((size_t)b * Nn + idx[k]) * 3 + c];
    }
    __syncthreads();

    // ---- build pair-sum table T2 (32768 elems, 64/thread), b1 folded into g==0 ----
    #pragma unroll 1
    for (int i = 0; i < 64; ++i) {
        int e = t + (i << 9);
        int h = e & 127, p = (e >> 7) & 63, g = e >> 13;
        int k1 = p >> 3, k2 = p & 7;
        float v = ptsl[k1 * 3 + 0] * W1[(6 * g + 0) * H1c + h]
                + ptsl[k1 * 3 + 1] * W1[(6 * g + 1) * H1c + h]
                + ptsl[k1 * 3 + 2] * W1[(6 * g + 2) * H1c + h]
                + ptsl[k2 * 3 + 0] * W1[(6 * g + 3) * H1c + h]
                + ptsl[k2 * 3 + 1] * W1[(6 * g + 4) * H1c + h]
                + ptsl[k2 * 3 + 2] * W1[(6 * g + 5) * H1c + h];
        if (g == 0) v += b1[h];
        T2f[(((g << 6) + p) * 32 + ((h >> 2) ^ (p & 7))) * 4 + (h & 3)] = v;
    }
    __syncthreads();

    const int lane = t & 63, wave = t >> 6;
    const int kh   = lane >> 5;          // k-half within fragment
    const int colm = lane & 31;          // row-offset (B n-dim) / j-offset (A m-dim)
    const int p0   = pib * 512;

    // per-tile row info (2 tiles of 32 rows per wave)
    int  baseq[2][4];
    int  swz[2][4];
    bool validr[2];
    #pragma unroll
    for (int tl = 0; tl < 2; ++tl) {
        int r = p0 + wave * 64 + tl * 32 + colm;
        validr[tl] = (r < Pn);
        int rc = r < Pn ? r : (Pn - 1);
        const int4* pp = (const int4*)(perms + ((size_t)b * Pn + rc) * 8);
        int4 pa = pp[0];
        int4 pb = pp[1];
        int pi0 = pa.x * 8 + pa.y;
        int pi1 = pa.z * 8 + pa.w;
        int pi2 = pb.x * 8 + pb.y;
        int pi3 = pb.z * 8 + pb.w;
        baseq[tl][0] = (0 * 64 + pi0) * 32;  swz[tl][0] = pi0 & 7;
        baseq[tl][1] = (1 * 64 + pi1) * 32;  swz[tl][1] = pi1 & 7;
        baseq[tl][2] = (2 * 64 + pi2) * 32;  swz[tl][2] = pi2 & 7;
        baseq[tl][3] = (3 * 64 + pi3) * 32;  swz[tl][3] = pi3 & 7;
    }

    f32x16 acc[2][2];
    #pragma unroll
    for (int tl = 0; tl < 2; ++tl)
        #pragma unroll
        for (int nt = 0; nt < 2; ++nt)
            #pragma unroll
            for (int q = 0; q < 16; ++q) acc[tl][nt][q] = 0.f;

    const float4* T2q = (const float4*)T2f;

    #pragma unroll 1
    for (int c = 0; c < 8; ++c) {
        // A-fragments (W2^T, pre-split) -- shared by both tiles
        s16x8 ah[2], al[2];
        #pragma unroll
        for (int nt = 0; nt < 2; ++nt) {
            int basei = (((c * 2 + nt) * 2 + kh) * 32 + colm) * 8;
            ah[nt] = *(const s16x8*)(w2hi + basei);
            al[nt] = *(const s16x8*)(w2lo + basei);
        }

        const int kq = c * 4 + kh * 2;   // quad index of this lane's first 4 h-values

        #pragma unroll
        for (int tl = 0; tl < 2; ++tl) {
            // gather h1[row][c*16 + kh*8 .. +8) = sum of 4 pair-table rows
            float4 r0 = T2q[baseq[tl][0] + (kq ^ swz[tl][0])];
            float4 r1 = T2q[baseq[tl][1] + (kq ^ swz[tl][1])];
            float4 r2 = T2q[baseq[tl][2] + (kq ^ swz[tl][2])];
            float4 r3 = T2q[baseq[tl][3] + (kq ^ swz[tl][3])];
            float s0x = r0.x + r1.x + r2.x + r3.x;
            float s0y = r0.y + r1.y + r2.y + r3.y;
            float s0z = r0.z + r1.z + r2.z + r3.z;
            float s0w = r0.w + r1.w + r2.w + r3.w;
            float4 q0 = T2q[baseq[tl][0] + ((kq + 1) ^ swz[tl][0])];
            float4 q1 = T2q[baseq[tl][1] + ((kq + 1) ^ swz[tl][1])];
            float4 q2 = T2q[baseq[tl][2] + ((kq + 1) ^ swz[tl][2])];
            float4 q3 = T2q[baseq[tl][3] + ((kq + 1) ^ swz[tl][3])];
            float s1x = q0.x + q1.x + q2.x + q3.x;
            float s1y = q0.y + q1.y + q2.y + q3.y;
            float s1z = q0.z + q1.z + q2.z + q3.z;
            float s1w = q0.w + q1.w + q2.w + q3.w;

            // relu + split into bf16 hi/lo B-fragments
            unsigned short bh[8], bl[8];
            split2(fmaxf(s0x, 0.f), bh[0], bl[0]);
            split2(fmaxf(s0y, 0.f), bh[1], bl[1]);
            split2(fmaxf(s0z, 0.f), bh[2], bl[2]);
            split2(fmaxf(s0w, 0.f), bh[3], bl[3]);
            split2(fmaxf(s1x, 0.f), bh[4], bl[4]);
            split2(fmaxf(s1y, 0.f), bh[5], bl[5]);
            split2(fmaxf(s1z, 0.f), bh[6], bl[6]);
            split2(fmaxf(s1w, 0.f), bh[7], bl[7]);
            s16x8 Bh, Bl;
            #pragma unroll
            for (int q = 0; q < 8; ++q) { Bh[q] = (short)bh[q]; Bl[q] = (short)bl[q]; }
            bf16x8 bhv = __builtin_bit_cast(bf16x8, Bh);
            bf16x8 blv = __builtin_bit_cast(bf16x8, Bl);

            #pragma unroll
            for (int nt = 0; nt < 2; ++nt) {
                bf16x8 Ah = __builtin_bit_cast(bf16x8, ah[nt]);
                bf16x8 Al = __builtin_bit_cast(bf16x8, al[nt]);
                acc[tl][nt] = __builtin_amdgcn_mfma_f32_32x32x16_bf16(Ah, bhv, acc[tl][nt], 0, 0, 0);
                acc[tl][nt] = __builtin_amdgcn_mfma_f32_32x32x16_bf16(Al, bhv, acc[tl][nt], 0, 0, 0);
                acc[tl][nt] = __builtin_amdgcn_mfma_f32_32x32x16_bf16(Ah, blv, acc[tl][nt], 0, 0, 0);
            }
        }
    }

    // ---- epilogue: +b2, relu, mask tail rows, reduce over the 32 rows (lanes) ----
    #pragma unroll
    for (int nt = 0; nt < 2; ++nt) {
        #pragma unroll
        for (int r = 0; r < 16; ++r) {
            int j = nt * 32 + (r & 3) + 8 * (r >> 2) + 4 * kh;   // verified C/D row mapping
            float bb = b2[j];
            float v = 0.f;
            #pragma unroll
            for (int tl = 0; tl < 2; ++tl) {
                float h2v = acc[tl][nt][r] + bb;
                v += validr[tl] ? fmaxf(h2v, 0.f) : 0.f;
            }
            v += __shfl_xor(v, 1);
            v += __shfl_xor(v, 2);
            v += __shfl_xor(v, 4);
            v += __shfl_xor(v, 8);
            v += __shfl_xor(v, 16);
            if (colm == 0) wred[wave][j] = v;
        }
    }
    __syncthreads();

    if (t < 64) {
        float s2 = 0.f;
        #pragma unroll
        for (int w = 0; w < 8; ++w) s2 += wred[w][t];
        Hs[t] = s2;
    }
    __syncthreads();

    if (t < NCc) {
        constexpr float invP = 1.f / (float)Pn;
        float s3 = 0.f;
        #pragma unroll
        for (int j = 0; j < 64; ++j) s3 = fmaf(W3[j * NCc + t], Hs[j], s3);
        float basev = (pib == 0) ? b3[t] : 0.f;
        atomicAdd(&out[b * NCc + t], basev + s3 * invP);
    }
}

extern "C" void kernel_launch(void* const* d_in, const int* in_sizes, int n_in,
                              void* d_out, int out_size, void* d_ws, size_t ws_size,
                              hipStream_t stream) {
    const float* x     = (const float*)d_in[0];
    const int*   idx   = (const int*)  d_in[1];
    const int*   perms = (const int*)  d_in[2];
    const float* W1    = (const float*)d_in[3];
    const float* b1    = (const float*)d_in[4];
    const float* W2    = (const float*)d_in[5];
    const float* b2    = (const float*)d_in[6];
    const float* W3    = (const float*)d_in[7];
    const float* b3    = (const float*)d_in[8];
    float* out = (float*)d_out;

    unsigned short* wsHi = (unsigned short*)d_ws;
    unsigned short* wsLo = wsHi + 8192;

    hipMemsetAsync(out, 0, (size_t)out_size * sizeof(float), stream);
    hipLaunchKernelGGL(prep_w2, dim3(32), dim3(256), 0, stream, W2, wsHi, wsLo);
    hipLaunchKernelGGL(mlp_mfma, dim3(Bn * 4), dim3(512), 0, stream,
                       x, idx, perms, W1, b1, b2, W3, b3, wsHi, wsLo, out);
}

// Round 4
// 187.020 us; speedup vs baseline: 2.0482x; 1.6465x over previous
//
#include <hip/hip_runtime.h>

typedef __bf16 bf16x8 __attribute__((ext_vector_type(8)));
typedef float  f32x16 __attribute__((ext_vector_type(16)));

constexpr int Bn = 512;
constexpr int Nn = 1024;
constexpr int Pn = 2016;
constexpr int H1c = 128;
constexpr int H2c = 64;
constexpr int NCc = 40;

// split fp32 v into bf16 hi + bf16 lo (v ~= hi + lo), RNE
__device__ __forceinline__ void split2(float v, unsigned short& hi, unsigned short& lo) {
    unsigned u  = __float_as_uint(v);
    unsigned r  = u + 0x7fffu + ((u >> 16) & 1u);
    hi = (unsigned short)(r >> 16);
    float hf = __uint_as_float(r & 0xffff0000u);
    unsigned u2 = __float_as_uint(v - hf);
    unsigned r2 = u2 + 0x7fffu + ((u2 >> 16) & 1u);
    lo = (unsigned short)(r2 >> 16);
}

// Pre-split W2 (128x64 f32) + b2 into MFMA-A-fragment-ready bf16 hi/lo arrays.
// idx = (((c*2+nt)*2 + kh)*32 + colm)*8 + jj ; c<8: W2[k= c*16+kh*8+jj][j= nt*32+colm]
// c==8: bias chunk — b2[j] in k-slot 0 (kh==0 && jj==0), zeros elsewhere.
__global__ void prep_w2(const float* __restrict__ W2, const float* __restrict__ b2,
                        unsigned short* __restrict__ hi, unsigned short* __restrict__ lo) {
    int i = blockIdx.x * 256 + threadIdx.x;
    if (i >= 9216) return;
    int jj = i & 7, colm = (i >> 3) & 31, kh = (i >> 8) & 1, nt = (i >> 9) & 1, c = i >> 10;
    int j = nt * 32 + colm;
    float v;
    if (c < 8) { int k = c * 16 + kh * 8 + jj; v = W2[k * H2c + j]; }
    else       { v = (kh == 0 && jj == 0) ? b2[j] : 0.f; }
    unsigned short h, l;
    split2(v, h, l);
    hi[i] = h;
    lo[i] = l;
}

__global__ __launch_bounds__(1024)
void mlp_mfma(const float* __restrict__ x, const int* __restrict__ idx,
              const int* __restrict__ perms,
              const float* __restrict__ W1, const float* __restrict__ b1,
              const float* __restrict__ W3, const float* __restrict__ b3,
              const unsigned short* __restrict__ w2hi,
              const unsigned short* __restrict__ w2lo,
              float* __restrict__ out)
{
    // T2[g][p][h] swizzled at float4 granularity:
    // float index = ((g*64+p)*32 + ((h>>2) ^ (p&7)))*4 + (h&3)
    __shared__ float T2f[4 * 64 * 128];      // 128 KiB
    __shared__ float ptsl[24];
    __shared__ float wred[16][64];
    __shared__ float Hs[64];

    const int t = threadIdx.x;
    const int b = blockIdx.x;

    if (t < 24) {
        int k = t / 3, c = t % 3;
        ptsl[t] = x[((size_t)b * Nn + idx[k]) * 3 + c];
    }
    __syncthreads();

    // ---- build pair-sum table T2 (32768 elems, 32/thread), b1 folded into g==0 ----
    #pragma unroll 1
    for (int i = 0; i < 32; ++i) {
        int e = t + (i << 10);
        int h = e & 127, p = (e >> 7) & 63, g = e >> 13;
        int k1 = p >> 3, k2 = p & 7;
        float v = ptsl[k1 * 3 + 0] * W1[(6 * g + 0) * H1c + h]
                + ptsl[k1 * 3 + 1] * W1[(6 * g + 1) * H1c + h]
                + ptsl[k1 * 3 + 2] * W1[(6 * g + 2) * H1c + h]
                + ptsl[k2 * 3 + 0] * W1[(6 * g + 3) * H1c + h]
                + ptsl[k2 * 3 + 1] * W1[(6 * g + 4) * H1c + h]
                + ptsl[k2 * 3 + 2] * W1[(6 * g + 5) * H1c + h];
        if (g == 0) v += b1[h];
        T2f[(((g << 6) + p) * 32 + ((h >> 2) ^ (p & 7))) * 4 + (h & 3)] = v;
    }
    __syncthreads();

    const int lane = t & 63, wave = t >> 6;
    const int kh = lane >> 5, colm = lane & 31;

    const float4* T2q = (const float4*)T2f;

    float vsum[32];
    #pragma unroll
    for (int q = 0; q < 32; ++q) vsum[q] = 0.f;

    // one-hot B vector for the bias MFMA chunk (k-slot 0 lives in kh==0, jj==0)
    bf16x8 Bone = {};
    if (kh == 0) Bone[0] = (__bf16)1.0f;

    // 63 tiles of 32 rows; wave w handles tiles w, w+16, w+32, w+48 (<63)
    #pragma unroll 1
    for (int tj = 0; tj < 4; ++tj) {
        const int tile = wave + (tj << 4);
        if (tile >= 63) break;

        const int4* pp = (const int4*)(perms + ((size_t)b * Pn + (tile << 5) + colm) * 8);
        int4 pa = pp[0];
        int4 pb = pp[1];
        int pi0 = pa.x * 8 + pa.y;
        int pi1 = pa.z * 8 + pa.w;
        int pi2 = pb.x * 8 + pb.y;
        int pi3 = pb.z * 8 + pb.w;
        const int bq0 = pi0 * 32,         sz0 = pi0 & 7;
        const int bq1 = (64  + pi1) * 32, sz1 = pi1 & 7;
        const int bq2 = (128 + pi2) * 32, sz2 = pi2 & 7;
        const int bq3 = (192 + pi3) * 32, sz3 = pi3 & 7;

        f32x16 acc0, acc1;
        #pragma unroll
        for (int q = 0; q < 16; ++q) { acc0[q] = 0.f; acc1[q] = 0.f; }

        #pragma unroll 1
        for (int c = 0; c < 8; ++c) {
            const int kq = c * 4 + kh * 2;
            // gather h1 chunk: sum of 4 pair-table rows (2 float4 quads each)
            float4 r0 = T2q[bq0 + (kq ^ sz0)];
            float4 r1 = T2q[bq1 + (kq ^ sz1)];
            float4 r2 = T2q[bq2 + (kq ^ sz2)];
            float4 r3 = T2q[bq3 + (kq ^ sz3)];
            float4 q0 = T2q[bq0 + ((kq + 1) ^ sz0)];
            float4 q1 = T2q[bq1 + ((kq + 1) ^ sz1)];
            float4 q2 = T2q[bq2 + ((kq + 1) ^ sz2)];
            float4 q3 = T2q[bq3 + ((kq + 1) ^ sz3)];
            float s0 = fmaxf(r0.x + r1.x + r2.x + r3.x, 0.f);
            float s1 = fmaxf(r0.y + r1.y + r2.y + r3.y, 0.f);
            float s2 = fmaxf(r0.z + r1.z + r2.z + r3.z, 0.f);
            float s3 = fmaxf(r0.w + r1.w + r2.w + r3.w, 0.f);
            float s4 = fmaxf(q0.x + q1.x + q2.x + q3.x, 0.f);
            float s5 = fmaxf(q0.y + q1.y + q2.y + q3.y, 0.f);
            float s6 = fmaxf(q0.z + q1.z + q2.z + q3.z, 0.f);
            float s7 = fmaxf(q0.w + q1.w + q2.w + q3.w, 0.f);

            // hi/lo split via native casts (compiler pairs into v_cvt_pk_bf16_f32)
            __bf16 h0 = (__bf16)s0, h1 = (__bf16)s1, h2 = (__bf16)s2, h3 = (__bf16)s3;
            __bf16 h4 = (__bf16)s4, h5 = (__bf16)s5, h6 = (__bf16)s6, h7 = (__bf16)s7;
            bf16x8 Bh = {h0, h1, h2, h3, h4, h5, h6, h7};
            bf16x8 Bl = {(__bf16)(s0 - (float)h0), (__bf16)(s1 - (float)h1),
                         (__bf16)(s2 - (float)h2), (__bf16)(s3 - (float)h3),
                         (__bf16)(s4 - (float)h4), (__bf16)(s5 - (float)h5),
                         (__bf16)(s6 - (float)h6), (__bf16)(s7 - (float)h7)};

            const int bi0 = (((c * 2 + 0) * 2 + kh) * 32 + colm) * 8;
            const int bi1 = (((c * 2 + 1) * 2 + kh) * 32 + colm) * 8;
            bf16x8 Ah0 = *(const bf16x8*)(w2hi + bi0);
            bf16x8 Al0 = *(const bf16x8*)(w2lo + bi0);
            bf16x8 Ah1 = *(const bf16x8*)(w2hi + bi1);
            bf16x8 Al1 = *(const bf16x8*)(w2lo + bi1);
            acc0 = __builtin_amdgcn_mfma_f32_32x32x16_bf16(Ah0, Bh, acc0, 0, 0, 0);
            acc0 = __builtin_amdgcn_mfma_f32_32x32x16_bf16(Al0, Bh, acc0, 0, 0, 0);
            acc0 = __builtin_amdgcn_mfma_f32_32x32x16_bf16(Ah0, Bl, acc0, 0, 0, 0);
            acc1 = __builtin_amdgcn_mfma_f32_32x32x16_bf16(Ah1, Bh, acc1, 0, 0, 0);
            acc1 = __builtin_amdgcn_mfma_f32_32x32x16_bf16(Al1, Bh, acc1, 0, 0, 0);
            acc1 = __builtin_amdgcn_mfma_f32_32x32x16_bf16(Ah1, Bl, acc1, 0, 0, 0);
        }

        // ---- bias via MFMA (c==8 chunk, one-hot B) ----
        {
            const int bi0 = (((16 + 0) * 2 + kh) * 32 + colm) * 8;
            const int bi1 = (((16 + 1) * 2 + kh) * 32 + colm) * 8;
            bf16x8 Ah0 = *(const bf16x8*)(w2hi + bi0);
            bf16x8 Al0 = *(const bf16x8*)(w2lo + bi0);
            bf16x8 Ah1 = *(const bf16x8*)(w2hi + bi1);
            bf16x8 Al1 = *(const bf16x8*)(w2lo + bi1);
            acc0 = __builtin_amdgcn_mfma_f32_32x32x16_bf16(Ah0, Bone, acc0, 0, 0, 0);
            acc0 = __builtin_amdgcn_mfma_f32_32x32x16_bf16(Al0, Bone, acc0, 0, 0, 0);
            acc1 = __builtin_amdgcn_mfma_f32_32x32x16_bf16(Ah1, Bone, acc1, 0, 0, 0);
            acc1 = __builtin_amdgcn_mfma_f32_32x32x16_bf16(Al1, Bone, acc1, 0, 0, 0);
        }

        // ---- relu + accumulate into per-lane running sum (layer-3 commutes with mean) ----
        #pragma unroll
        for (int r = 0; r < 16; ++r) vsum[r]      += fmaxf(acc0[r], 0.f);
        #pragma unroll
        for (int r = 0; r < 16; ++r) vsum[16 + r] += fmaxf(acc1[r], 0.f);
    }

    // ---- reduce over the 32 rows (lanes) per wave ----
    #pragma unroll
    for (int nt = 0; nt < 2; ++nt) {
        #pragma unroll
        for (int r = 0; r < 16; ++r) {
            int j = nt * 32 + (r & 3) + 8 * (r >> 2) + 4 * kh;   // verified C/D row mapping
            float v = vsum[nt * 16 + r];
            v += __shfl_xor(v, 1);
            v += __shfl_xor(v, 2);
            v += __shfl_xor(v, 4);
            v += __shfl_xor(v, 8);
            v += __shfl_xor(v, 16);
            if (colm == 0) wred[wave][j] = v;
        }
    }
    __syncthreads();

    if (t < 64) {
        float s2 = 0.f;
        #pragma unroll
        for (int w = 0; w < 16; ++w) s2 += wred[w][t];
        Hs[t] = s2;
    }
    __syncthreads();

    // ---- layer 3 once per block; block owns batch b -> direct store ----
    if (t < NCc) {
        constexpr float invP = 1.f / (float)Pn;
        float s3 = 0.f;
        #pragma unroll
        for (int j = 0; j < 64; ++j) s3 = fmaf(W3[j * NCc + t], Hs[j], s3);
        out[b * NCc + t] = b3[t] + s3 * invP;
    }
}

extern "C" void kernel_launch(void* const* d_in, const int* in_sizes, int n_in,
                              void* d_out, int out_size, void* d_ws, size_t ws_size,
                              hipStream_t stream) {
    const float* x     = (const float*)d_in[0];
    const int*   idx   = (const int*)  d_in[1];
    const int*   perms = (const int*)  d_in[2];
    const float* W1    = (const float*)d_in[3];
    const float* b1    = (const float*)d_in[4];
    const float* W2    = (const float*)d_in[5];
    const float* b2    = (const float*)d_in[6];
    const float* W3    = (const float*)d_in[7];
    const float* b3    = (const float*)d_in[8];
    float* out = (float*)d_out;

    unsigned short* wsHi = (unsigned short*)d_ws;
    unsigned short* wsLo = wsHi + 9216;

    hipLaunchKernelGGL(prep_w2, dim3(36), dim3(256), 0, stream, W2, b2, wsHi, wsLo);
    hipLaunchKernelGGL(mlp_mfma, dim3(Bn), dim3(1024), 0, stream,
                       x, idx, perms, W1, b1, W3, b3, wsHi, wsLo, out);
}

// Round 7
// 176.163 us; speedup vs baseline: 2.1744x; 1.0616x over previous
//
#include <hip/hip_runtime.h>

typedef __bf16 bf16x8 __attribute__((ext_vector_type(8)));
typedef _Float16 hf8  __attribute__((ext_vector_type(8)));
typedef float  f32x16 __attribute__((ext_vector_type(16)));

constexpr int Bn = 512;
constexpr int Nn = 1024;
constexpr int Pn = 2016;
constexpr int H1c = 128;
constexpr int H2c = 64;
constexpr int NCc = 40;

// split fp32 v into bf16 hi + bf16 lo (v ~= hi + lo), RNE
__device__ __forceinline__ void split2(float v, unsigned short& hi, unsigned short& lo) {
    unsigned u  = __float_as_uint(v);
    unsigned r  = u + 0x7fffu + ((u >> 16) & 1u);
    hi = (unsigned short)(r >> 16);
    float hf = __uint_as_float(r & 0xffff0000u);
    unsigned u2 = __float_as_uint(v - hf);
    unsigned r2 = u2 + 0x7fffu + ((u2 >> 16) & 1u);
    lo = (unsigned short)(r2 >> 16);
}

// Pre-split W2 (128x64 f32) + b2 into MFMA-A-fragment-ready bf16 hi/lo arrays
// for mfma_f32_32x32x16_bf16 (PROVEN layout, R3/R4 passed):
// idx = (((c*2+nt)*2 + kh)*32 + colm)*8 + jj ; c<8: W2[k= c*16+kh*8+jj][j= nt*32+colm]
// c==8: bias chunk — b2[j] in k-slot 0 (kh==0 && jj==0), zeros elsewhere.
__global__ void prep_w2(const float* __restrict__ W2, const float* __restrict__ b2,
                        unsigned short* __restrict__ hi, unsigned short* __restrict__ lo) {
    int i = blockIdx.x * 256 + threadIdx.x;
    if (i >= 9216) return;
    int jj = i & 7, colm = (i >> 3) & 31, kh = (i >> 8) & 1, nt = (i >> 9) & 1, c = i >> 10;
    int j = nt * 32 + colm;
    float v;
    if (c < 8) { int k = c * 16 + kh * 8 + jj; v = W2[k * H2c + j]; }
    else       { v = (kh == 0 && jj == 0) ? b2[j] : 0.f; }
    unsigned short h, l;
    split2(v, h, l);
    hi[i] = h;
    lo[i] = l;
}

__global__ __launch_bounds__(1024)
void mlp_mfma(const float* __restrict__ x, const int* __restrict__ idx,
              const int* __restrict__ perms,
              const float* __restrict__ W1, const float* __restrict__ b1,
              const float* __restrict__ W3, const float* __restrict__ b3,
              const unsigned short* __restrict__ w2hi,
              const unsigned short* __restrict__ w2lo,
              float* __restrict__ out)
{
    // fp16 pair-sum table: entry (gp = g*64 + k1*8+k2, h) at half-index
    //   gp*128 + ((h>>3) ^ (gp&15))*8 + (h&7)     (16B-line XOR swizzle)
    __shared__ _Float16 T2h[256 * 128];   // 64 KiB = 32768 f16 entries
    __shared__ float ptsl[24];
    __shared__ float wred[16][64];        // 4 KiB
    __shared__ float Hs[64];

    const int t = threadIdx.x, b = blockIdx.x;

    if (t < 24) {
        int k = t / 3, c = t % 3;
        ptsl[t] = x[((size_t)b * Nn + idx[k]) * 3 + c];
    }
    __syncthreads();

    // ---- build T2: 32768 entries, 32 PER THREAD (R5/R6 bug: was 16 -> half
    // the table uninitialized), b1 folded into g==0 ----
    #pragma unroll 1
    for (int i = 0; i < 32; ++i) {
        int e = t + (i << 10);
        int h = e & 127, gp = e >> 7;          // gp in 0..255
        int g = gp >> 6, p = gp & 63, k1 = p >> 3, k2 = p & 7;
        float v = ptsl[k1 * 3 + 0] * W1[(6 * g + 0) * H1c + h]
                + ptsl[k1 * 3 + 1] * W1[(6 * g + 1) * H1c + h]
                + ptsl[k1 * 3 + 2] * W1[(6 * g + 2) * H1c + h]
                + ptsl[k2 * 3 + 0] * W1[(6 * g + 3) * H1c + h]
                + ptsl[k2 * 3 + 1] * W1[(6 * g + 4) * H1c + h]
                + ptsl[k2 * 3 + 2] * W1[(6 * g + 5) * H1c + h];
        if (g == 0) v += b1[h];
        T2h[(gp << 7) + (((h >> 3) ^ (gp & 15)) << 3) + (h & 7)] = (_Float16)v;
    }
    __syncthreads();

    const int lane = t & 63, wave = t >> 6;
    const int kh = lane >> 5, colm = lane & 31;

    float vsum[32];
    #pragma unroll
    for (int q = 0; q < 32; ++q) vsum[q] = 0.f;

    // one-hot B vector for the bias MFMA chunk (k-slot 0 lives in kh==0, jj==0)
    bf16x8 Bone = {};
    if (kh == 0) Bone[0] = (__bf16)1.0f;

    // 63 tiles of 32 rows; wave w handles tiles w, w+16, w+32, w+48 (<63)
    #pragma unroll 1
    for (int tj = 0; tj < 4; ++tj) {
        const int tile = wave + (tj << 4);
        if (tile >= 63) break;

        const int4* pp = (const int4*)(perms + ((size_t)b * Pn + (tile << 5) + colm) * 8);
        int4 pa = pp[0];
        int4 pb = pp[1];
        const int gp0 = pa.x * 8 + pa.y;
        const int gp1 = 64  + pa.z * 8 + pa.w;
        const int gp2 = 128 + pb.x * 8 + pb.y;
        const int gp3 = 192 + pb.z * 8 + pb.w;
        const int bq0 = gp0 << 7, sz0 = gp0 & 15;
        const int bq1 = gp1 << 7, sz1 = gp1 & 15;
        const int bq2 = gp2 << 7, sz2 = gp2 & 15;
        const int bq3 = gp3 << 7, sz3 = gp3 & 15;

        f32x16 acc0, acc1;
        #pragma unroll
        for (int q = 0; q < 16; ++q) { acc0[q] = 0.f; acc1[q] = 0.f; }

        #pragma unroll 1
        for (int c = 0; c < 8; ++c) {
            const int L = c * 2 + kh;     // h-block of 8 this lane-half needs
            // gather h1 chunk: ONE b128 per pair-row (fp16), pk-add tree
            hf8 r0 = *(const hf8*)&T2h[bq0 + ((L ^ sz0) << 3)];
            hf8 r1 = *(const hf8*)&T2h[bq1 + ((L ^ sz1) << 3)];
            hf8 r2 = *(const hf8*)&T2h[bq2 + ((L ^ sz2) << 3)];
            hf8 r3 = *(const hf8*)&T2h[bq3 + ((L ^ sz3) << 3)];
            hf8 s = (r0 + r1) + (r2 + r3);       // v_pk_add_f16
            hf8 z = {};
            s = __builtin_elementwise_max(s, z); // v_pk_max_f16 (relu)

            // convert to f32, then bf16 hi + lo B-fragments (R4-proven numerics)
            float sf0 = (float)s[0], sf1 = (float)s[1], sf2 = (float)s[2], sf3 = (float)s[3];
            float sf4 = (float)s[4], sf5 = (float)s[5], sf6 = (float)s[6], sf7 = (float)s[7];
            __bf16 h0 = (__bf16)sf0, h1 = (__bf16)sf1, h2 = (__bf16)sf2, h3 = (__bf16)sf3;
            __bf16 h4 = (__bf16)sf4, h5 = (__bf16)sf5, h6 = (__bf16)sf6, h7 = (__bf16)sf7;
            bf16x8 Bh = {h0, h1, h2, h3, h4, h5, h6, h7};
            bf16x8 Bl = {(__bf16)(sf0 - (float)h0), (__bf16)(sf1 - (float)h1),
                         (__bf16)(sf2 - (float)h2), (__bf16)(sf3 - (float)h3),
                         (__bf16)(sf4 - (float)h4), (__bf16)(sf5 - (float)h5),
                         (__bf16)(sf6 - (float)h6), (__bf16)(sf7 - (float)h7)};

            const int bi0 = (((c * 2 + 0) * 2 + kh) * 32 + colm) * 8;
            const int bi1 = (((c * 2 + 1) * 2 + kh) * 32 + colm) * 8;
            bf16x8 Ah0 = *(const bf16x8*)(w2hi + bi0);
            bf16x8 Al0 = *(const bf16x8*)(w2lo + bi0);
            bf16x8 Ah1 = *(const bf16x8*)(w2hi + bi1);
            bf16x8 Al1 = *(const bf16x8*)(w2lo + bi1);
            acc0 = __builtin_amdgcn_mfma_f32_32x32x16_bf16(Ah0, Bh, acc0, 0, 0, 0);
            acc0 = __builtin_amdgcn_mfma_f32_32x32x16_bf16(Al0, Bh, acc0, 0, 0, 0);
            acc0 = __builtin_amdgcn_mfma_f32_32x32x16_bf16(Ah0, Bl, acc0, 0, 0, 0);
            acc1 = __builtin_amdgcn_mfma_f32_32x32x16_bf16(Ah1, Bh, acc1, 0, 0, 0);
            acc1 = __builtin_amdgcn_mfma_f32_32x32x16_bf16(Al1, Bh, acc1, 0, 0, 0);
            acc1 = __builtin_amdgcn_mfma_f32_32x32x16_bf16(Ah1, Bl, acc1, 0, 0, 0);
        }

        // ---- bias via MFMA (c==8 chunk, one-hot B) ----
        {
            const int bi0 = (((16 + 0) * 2 + kh) * 32 + colm) * 8;
            const int bi1 = (((16 + 1) * 2 + kh) * 32 + colm) * 8;
            bf16x8 Ah0 = *(const bf16x8*)(w2hi + bi0);
            bf16x8 Al0 = *(const bf16x8*)(w2lo + bi0);
            bf16x8 Ah1 = *(const bf16x8*)(w2hi + bi1);
            bf16x8 Al1 = *(const bf16x8*)(w2lo + bi1);
            acc0 = __builtin_amdgcn_mfma_f32_32x32x16_bf16(Ah0, Bone, acc0, 0, 0, 0);
            acc0 = __builtin_amdgcn_mfma_f32_32x32x16_bf16(Al0, Bone, acc0, 0, 0, 0);
            acc1 = __builtin_amdgcn_mfma_f32_32x32x16_bf16(Ah1, Bone, acc1, 0, 0, 0);
            acc1 = __builtin_amdgcn_mfma_f32_32x32x16_bf16(Al1, Bone, acc1, 0, 0, 0);
        }

        // ---- relu + accumulate into per-lane running sum (layer-3 commutes with mean) ----
        #pragma unroll
        for (int r = 0; r < 16; ++r) vsum[r]      += fmaxf(acc0[r], 0.f);
        #pragma unroll
        for (int r = 0; r < 16; ++r) vsum[16 + r] += fmaxf(acc1[r], 0.f);
    }

    // ---- reduce over the 32 rows (lanes) per wave ----
    #pragma unroll
    for (int nt = 0; nt < 2; ++nt) {
        #pragma unroll
        for (int r = 0; r < 16; ++r) {
            int j = nt * 32 + (r & 3) + 8 * (r >> 2) + 4 * kh;   // verified C/D row mapping
            float v = vsum[nt * 16 + r];
            v += __shfl_xor(v, 1);
            v += __shfl_xor(v, 2);
            v += __shfl_xor(v, 4);
            v += __shfl_xor(v, 8);
            v += __shfl_xor(v, 16);
            if (colm == 0) wred[wave][j] = v;
        }
    }
    __syncthreads();

    if (t < 64) {
        float s2 = 0.f;
        #pragma unroll
        for (int w = 0; w < 16; ++w) s2 += wred[w][t];
        Hs[t] = s2;
    }
    __syncthreads();

    // ---- layer 3 once per block; block owns batch b -> direct store ----
    if (t < NCc) {
        constexpr float invP = 1.f / (float)Pn;
        float s3 = 0.f;
        #pragma unroll
        for (int j = 0; j < 64; ++j) s3 = fmaf(W3[j * NCc + t], Hs[j], s3);
        out[b * NCc + t] = b3[t] + s3 * invP;
    }
}

extern "C" void kernel_launch(void* const* d_in, const int* in_sizes, int n_in,
                              void* d_out, int out_size, void* d_ws, size_t ws_size,
                              hipStream_t stream) {
    const float* x     = (const float*)d_in[0];
    const int*   idx   = (const int*)  d_in[1];
    const int*   perms = (const int*)  d_in[2];
    const float* W1    = (const float*)d_in[3];
    const float* b1    = (const float*)d_in[4];
    const float* W2    = (const float*)d_in[5];
    const float* b2    = (const float*)d_in[6];
    const float* W3    = (const float*)d_in[7];
    const float* b3    = (const float*)d_in[8];
    float* out = (float*)d_out;

    unsigned short* wsHi = (unsigned short*)d_ws;
    unsigned short* wsLo = wsHi + 9216;

    hipLaunchKernelGGL(prep_w2, dim3(36), dim3(256), 0, stream, W2, b2, wsHi, wsLo);
    hipLaunchKernelGGL(mlp_mfma, dim3(Bn), dim3(1024), 0, stream,
                       x, idx, perms, W1, b1, W3, b3, wsHi, wsLo, out);
}

// Round 8
// 162.310 us; speedup vs baseline: 2.3600x; 1.0853x over previous
//
#include <hip/hip_runtime.h>

typedef _Float16 hf8  __attribute__((ext_vector_type(8)));
typedef float  f32x16 __attribute__((ext_vector_type(16)));

constexpr int Bn = 512;
constexpr int Nn = 1024;
constexpr int Pn = 2016;
constexpr int H1c = 128;
constexpr int H2c = 64;
constexpr int NCc = 40;

// Pre-split W2 (128x64 f32) + b2 into f16 hi/lo A-fragments for
// mfma_f32_32x32x16_f16 (same operand geometry as the R4/R7-proven bf16 twin):
// idx = (((c*2+nt)*2 + kh)*32 + colm)*8 + jj ; c<8: W2[k= c*16+kh*8+jj][j= nt*32+colm]
// c==8: bias chunk — b2[j] in k-slot 0 (kh==0 && jj==0), zeros elsewhere.
__global__ void prep_w2(const float* __restrict__ W2, const float* __restrict__ b2,
                        _Float16* __restrict__ hi, _Float16* __restrict__ lo) {
    int i = blockIdx.x * 256 + threadIdx.x;
    if (i >= 9216) return;
    int jj = i & 7, colm = (i >> 3) & 31, kh = (i >> 8) & 1, nt = (i >> 9) & 1, c = i >> 10;
    int j = nt * 32 + colm;
    float v;
    if (c < 8) { int k = c * 16 + kh * 8 + jj; v = W2[k * H2c + j]; }
    else       { v = (kh == 0 && jj == 0) ? b2[j] : 0.f; }
    _Float16 h = (_Float16)v;            // RNE
    hi[i] = h;
    lo[i] = (_Float16)(v - (float)h);    // residual, rel err ~2^-22 combined
}

__global__ __launch_bounds__(1024)
void mlp_mfma(const float* __restrict__ x, const int* __restrict__ idx,
              const int* __restrict__ perms,
              const float* __restrict__ W1, const float* __restrict__ b1,
              const float* __restrict__ W3, const float* __restrict__ b3,
              const _Float16* __restrict__ w2hi,
              const _Float16* __restrict__ w2lo,
              float* __restrict__ out)
{
    // fp16 pair-sum table: entry (gp = g*64 + k1*8+k2, h) at half-index
    //   gp*128 + ((h>>3) ^ (gp&15))*8 + (h&7)     (16B-line XOR swizzle)
    __shared__ _Float16 T2h[256 * 128];   // 64 KiB = 32768 f16 entries
    __shared__ float ptsl[24];
    __shared__ float wred[16][64];        // 4 KiB
    __shared__ float Hs[64];

    const int t = threadIdx.x, b = blockIdx.x;

    if (t < 24) {
        int k = t / 3, c = t % 3;
        ptsl[t] = x[((size_t)b * Nn + idx[k]) * 3 + c];
    }
    __syncthreads();

    // ---- build T2: 32768 entries, 32 per thread, b1 folded into g==0 ----
    #pragma unroll 1
    for (int i = 0; i < 32; ++i) {
        int e = t + (i << 10);
        int h = e & 127, gp = e >> 7;          // gp in 0..255
        int g = gp >> 6, p = gp & 63, k1 = p >> 3, k2 = p & 7;
        float v = ptsl[k1 * 3 + 0] * W1[(6 * g + 0) * H1c + h]
                + ptsl[k1 * 3 + 1] * W1[(6 * g + 1) * H1c + h]
                + ptsl[k1 * 3 + 2] * W1[(6 * g + 2) * H1c + h]
                + ptsl[k2 * 3 + 0] * W1[(6 * g + 3) * H1c + h]
                + ptsl[k2 * 3 + 1] * W1[(6 * g + 4) * H1c + h]
                + ptsl[k2 * 3 + 2] * W1[(6 * g + 5) * H1c + h];
        if (g == 0) v += b1[h];
        T2h[(gp << 7) + (((h >> 3) ^ (gp & 15)) << 3) + (h & 7)] = (_Float16)v;
    }
    __syncthreads();

    const int lane = t & 63, wave = t >> 6;
    const int kh = lane >> 5, colm = lane & 31;

    float vsum[32];
    #pragma unroll
    for (int q = 0; q < 32; ++q) vsum[q] = 0.f;

    // one-hot B vector for the bias MFMA chunk (k-slot 0 lives in kh==0, e==0)
    hf8 Bone = {};
    if (kh == 0) Bone[0] = (_Float16)1.0f;

    // 63 tiles of 32 rows; wave w handles tiles w, w+16, w+32, w+48 (<63)
    #pragma unroll 1
    for (int tj = 0; tj < 4; ++tj) {
        const int tile = wave + (tj << 4);
        if (tile >= 63) break;

        const int4* pp = (const int4*)(perms + ((size_t)b * Pn + (tile << 5) + colm) * 8);
        int4 pa = pp[0];
        int4 pb = pp[1];
        const int gp0 = pa.x * 8 + pa.y;
        const int gp1 = 64  + pa.z * 8 + pa.w;
        const int gp2 = 128 + pb.x * 8 + pb.y;
        const int gp3 = 192 + pb.z * 8 + pb.w;
        const int bq0 = gp0 << 7, sz0 = gp0 & 15;
        const int bq1 = gp1 << 7, sz1 = gp1 & 15;
        const int bq2 = gp2 << 7, sz2 = gp2 & 15;
        const int bq3 = gp3 << 7, sz3 = gp3 & 15;

        f32x16 acc0, acc1;
        #pragma unroll
        for (int q = 0; q < 16; ++q) { acc0[q] = 0.f; acc1[q] = 0.f; }

        #pragma unroll 1
        for (int c = 0; c < 8; ++c) {
            const int L = c * 2 + kh;     // h-block of 8 this lane-half needs
            // gather h1 chunk: ONE b128 per pair-row (fp16), pk-add tree
            hf8 r0 = *(const hf8*)&T2h[bq0 + ((L ^ sz0) << 3)];
            hf8 r1 = *(const hf8*)&T2h[bq1 + ((L ^ sz1) << 3)];
            hf8 r2 = *(const hf8*)&T2h[bq2 + ((L ^ sz2) << 3)];
            hf8 r3 = *(const hf8*)&T2h[bq3 + ((L ^ sz3) << 3)];
            hf8 s = (r0 + r1) + (r2 + r3);       // v_pk_add_f16
            hf8 z = {};
            s = __builtin_elementwise_max(s, z); // v_pk_max_f16 (relu) -> exact f16 B

            const int bi0 = (((c * 2 + 0) * 2 + kh) * 32 + colm) * 8;
            const int bi1 = (((c * 2 + 1) * 2 + kh) * 32 + colm) * 8;
            hf8 Ah0 = *(const hf8*)(w2hi + bi0);
            hf8 Al0 = *(const hf8*)(w2lo + bi0);
            hf8 Ah1 = *(const hf8*)(w2hi + bi1);
            hf8 Al1 = *(const hf8*)(w2lo + bi1);
            acc0 = __builtin_amdgcn_mfma_f32_32x32x16_f16(Ah0, s, acc0, 0, 0, 0);
            acc0 = __builtin_amdgcn_mfma_f32_32x32x16_f16(Al0, s, acc0, 0, 0, 0);
            acc1 = __builtin_amdgcn_mfma_f32_32x32x16_f16(Ah1, s, acc1, 0, 0, 0);
            acc1 = __builtin_amdgcn_mfma_f32_32x32x16_f16(Al1, s, acc1, 0, 0, 0);
        }

        // ---- bias via MFMA (c==8 chunk, one-hot B) ----
        {
            const int bi0 = (((16 + 0) * 2 + kh) * 32 + colm) * 8;
            const int bi1 = (((16 + 1) * 2 + kh) * 32 + colm) * 8;
            hf8 Ah0 = *(const hf8*)(w2hi + bi0);
            hf8 Al0 = *(const hf8*)(w2lo + bi0);
            hf8 Ah1 = *(const hf8*)(w2hi + bi1);
            hf8 Al1 = *(const hf8*)(w2lo + bi1);
            acc0 = __builtin_amdgcn_mfma_f32_32x32x16_f16(Ah0, Bone, acc0, 0, 0, 0);
            acc0 = __builtin_amdgcn_mfma_f32_32x32x16_f16(Al0, Bone, acc0, 0, 0, 0);
            acc1 = __builtin_amdgcn_mfma_f32_32x32x16_f16(Ah1, Bone, acc1, 0, 0, 0);
            acc1 = __builtin_amdgcn_mfma_f32_32x32x16_f16(Al1, Bone, acc1, 0, 0, 0);
        }

        // ---- relu + accumulate into per-lane running sum (layer-3 commutes with mean) ----
        #pragma unroll
        for (int r = 0; r < 16; ++r) vsum[r]      += fmaxf(acc0[r], 0.f);
        #pragma unroll
        for (int r = 0; r < 16; ++r) vsum[16 + r] += fmaxf(acc1[r], 0.f);
    }

    // ---- reduce over the 32 rows (lanes) per wave ----
    #pragma unroll
    for (int nt = 0; nt < 2; ++nt) {
        #pragma unroll
        for (int r = 0; r < 16; ++r) {
            int j = nt * 32 + (r & 3) + 8 * (r >> 2) + 4 * kh;   // verified C/D row mapping
            float v = vsum[nt * 16 + r];
            v += __shfl_xor(v, 1);
            v += __shfl_xor(v, 2);
            v += __shfl_xor(v, 4);
            v += __shfl_xor(v, 8);
            v += __shfl_xor(v, 16);
            if (colm == 0) wred[wave][j] = v;
        }
    }
    __syncthreads();

    if (t < 64) {
        float s2 = 0.f;
        #pragma unroll
        for (int w = 0; w < 16; ++w) s2 += wred[w][t];
        Hs[t] = s2;
    }
    __syncthreads();

    // ---- layer 3 once per block; block owns batch b -> direct store ----
    if (t < NCc) {
        constexpr float invP = 1.f / (float)Pn;
        float s3 = 0.f;
        #pragma unroll
        for (int j = 0; j < 64; ++j) s3 = fmaf(W3[j * NCc + t], Hs[j], s3);
        out[b * NCc + t] = b3[t] + s3 * invP;
    }
}

extern "C" void kernel_launch(void* const* d_in, const int* in_sizes, int n_in,
                              void* d_out, int out_size, void* d_ws, size_t ws_size,
                              hipStream_t stream) {
    const float* x     = (const float*)d_in[0];
    const int*   idx   = (const int*)  d_in[1];
    const int*   perms = (const int*)  d_in[2];
    const float* W1    = (const float*)d_in[3];
    const float* b1    = (const float*)d_in[4];
    const float* W2    = (const float*)d_in[5];
    const float* b2    = (const float*)d_in[6];
    const float* W3    = (const float*)d_in[7];
    const float* b3    = (const float*)d_in[8];
    float* out = (float*)d_out;

    _Float16* wsHi = (_Float16*)d_ws;
    _Float16* wsLo = wsHi + 9216;

    hipLaunchKernelGGL(prep_w2, dim3(36), dim3(256), 0, stream, W2, b2, wsHi, wsLo);
    hipLaunchKernelGGL(mlp_mfma, dim3(Bn), dim3(1024), 0, stream,
                       x, idx, perms, W1, b1, W3, b3, wsHi, wsLo, out);
}